// Round 9
// baseline (350.002 us; speedup 1.0000x reference)
//
#include <hip/hip_runtime.h>

#define EMB 128
#define W1LD 532  // PRED_IN
#define KP 160    // padded K for MFMA (138 -> 160)
#define ST 264    // LDS row stride (u16) in node path

typedef unsigned long long u64;
typedef unsigned short u16;
typedef __attribute__((ext_vector_type(8))) short short8;
typedef __attribute__((ext_vector_type(4))) float f32x4;

__device__ __forceinline__ u16 f2bf(float x) {
    unsigned u = __float_as_uint(x);
    unsigned r = (u + 0x7fffu + ((u >> 16) & 1u)) >> 16;
    return (u16)r;
}
__device__ __forceinline__ float bf2f_lo(unsigned u) { return __uint_as_float(u << 16); }
__device__ __forceinline__ float bf2f_hi(unsigned u) { return __uint_as_float(u & 0xffff0000u); }

// round-1 mean, unpacked inline from packed accumulator
__device__ __forceinline__ float2 unpack1_mean(u64 a) {
    float c = (float)(unsigned)(a >> 42);
    float inv = (1.0f / 8192.0f) / fmaxf(c, 1.0f);
    float2 v;
    v.x = (float)(unsigned)(a & 0x1FFFFFull) * inv;
    v.y = (float)(unsigned)((a >> 21) & 0x1FFFFFull) * inv;
    return v;
}

// ---------------------------------------------------------------------------
// K1: scatter1 (blocks 0..ns-1)  ||  prep (blocks ns..ns+KP+NREL)
// scatter pack: [x*2^13:21b][y*2^13:21b][count:22b], 1 u64 atomic per direction
// prep: WBF (bf16 MFMA B-frag order), qWb (f32), Rbf (bf16)
// ---------------------------------------------------------------------------

__global__ __launch_bounds__(256) void k1_scatter1_prep(
    const int* __restrict__ h_id, const int* __restrict__ t_id,
    const float* __restrict__ topic,
    u64* __restrict__ acc_t, u64* __restrict__ acc_h,
    const float* __restrict__ W1, const float* __restrict__ q,
    const float* __restrict__ rel, const float* __restrict__ b1,
    u16* __restrict__ WBF, float* __restrict__ qWb, u16* __restrict__ Rbf,
    int E, int ns, int NREL)
{
    const int bid = blockIdx.x, t = threadIdx.x;
    if (bid < ns) {
        int e = bid * 256 + t;
        if (e >= E) return;
        int h = h_id[e], tt = t_id[e];
        float2 th = *(const float2*)(topic + 2 * h);
        float2 tv = *(const float2*)(topic + 2 * tt);
        u64 p1 = (u64)__float2uint_rn(th.x * 8192.0f)
               | ((u64)__float2uint_rn(th.y * 8192.0f) << 21)
               | (1ull << 42);
        u64 p3 = (u64)__float2uint_rn(tv.x * 8192.0f)
               | ((u64)__float2uint_rn(tv.y * 8192.0f) << 21)
               | (1ull << 42);
        atomicAdd(&acc_t[tt], p1);
        atomicAdd(&acc_h[h], p3);
        return;
    }
    const int pb = bid - ns;
    if (pb < KP) {
        int k = pb, n = t;
        float v = 0.0f;
        if (k < 138) {
            v = (n < 128) ? W1[(size_t)n * W1LD + 128 + k]
                          : W1[(size_t)(n - 128) * W1LD + 394 + k];
        }
        int kstep = k >> 5, quad = (k >> 3) & 3, j = k & 7;
        WBF[(((size_t)(kstep * 4 + quad) * 256 + n) << 3) + j] = f2bf(v);
        return;
    }
    int b = pb - KP;   // 0 -> qWb ; 1..NREL -> relation b-1
    __shared__ float v[EMB];
    if (t < EMB) v[t] = (b == 0) ? q[t] : rel[(size_t)(b - 1) * EMB + t];
    __syncthreads();
    if (t < EMB) {
        const float* w = W1 + (size_t)t * W1LD + (b == 0 ? 0 : 266);
        float s = 0.0f;
#pragma unroll
        for (int k = 0; k < EMB; k += 4) {
            float4 wv = *(const float4*)(w + k);
            s += wv.x * v[k] + wv.y * v[k + 1] + wv.z * v[k + 2] + wv.w * v[k + 3];
        }
        if (b == 0) qWb[t] = s + b1[t];
        else        Rbf[(size_t)(b - 1) * EMB + t] = f2bf(s);
    }
}

// ---------------------------------------------------------------------------
// K2: interleaved  odd blocks -> scatter2 ; even blocks -> node MFMA GEMM.
// node computes A/B WITHOUT dde2/dde4 (those 4 tail dims are zeroed); the
// missing rank-4 term is added in edge_pred. No acc2 reads here -> no race
// with concurrent scatter2 blocks.
// Round 2 pack: [x*2^20 : 32b][y*2^20 : 32b]
// ---------------------------------------------------------------------------

__global__ __launch_bounds__(256) void k2_scatter2_node(
    const int* __restrict__ h_id, const int* __restrict__ t_id,
    const u64* __restrict__ acc1_t, const u64* __restrict__ acc1_h,
    u64* __restrict__ acc2_t, u64* __restrict__ acc2_h,
    const float* __restrict__ ent, const float* __restrict__ nte,
    const float* __restrict__ topic,
    const u16* __restrict__ WBF, const float* __restrict__ qWb,
    u16* __restrict__ A, u16* __restrict__ B,
    int E, int ns, int NT, int N, int nn)
{
    __shared__ __align__(16) u16 lds[32 * ST];
    const int bid = blockIdx.x, t = threadIdx.x;
    const int half = bid >> 1;

    if (bid & 1) {
        // ---------------- scatter2 ----------------
        if (half >= ns) return;
        int e = half * 256 + t;
        if (e >= E) return;
        int h = h_id[e], tt = t_id[e];
        float2 v1 = unpack1_mean(acc1_t[h]);   // dde1[h]
        float2 v3 = unpack1_mean(acc1_h[tt]);  // dde3[t]
        const float sc = 1048576.0f;  // 2^20
        u64 p2 = (u64)__float2uint_rn(v1.x * sc)
               | ((u64)__float2uint_rn(v1.y * sc) << 32);
        u64 p4 = (u64)__float2uint_rn(v3.x * sc)
               | ((u64)__float2uint_rn(v3.y * sc) << 32);
        atomicAdd(&acc2_t[tt], p2);
        atomicAdd(&acc2_h[h], p4);
        return;
    }

    // ---------------- node GEMM ----------------
    if (half >= nn) return;
    const int lane = t & 63;
    const int w    = t >> 6;
    const int ln15 = lane & 15;
    const int quad = lane >> 4;
    const int m0   = (w & 1) * 16;
    const int n0   = (w >> 1) * 128;
    const int nblk = half * 32;

    {   // stage dense features as bf16: thread -> node m=t>>3, 16 k-elems
        int m  = t >> 3;
        int kq = (t & 7) << 4;
        int gn = nblk + m;
        const float* src = (gn < N) ? ((gn < NT) ? ent + (size_t)gn * EMB + kq
                                                 : nte + kq)
                                    : nte;
        u16 pk[16];
#pragma unroll
        for (int p = 0; p < 4; p++) {
            float4 v = (gn < N) ? *(const float4*)(src + 4 * p)
                                : make_float4(0.f, 0.f, 0.f, 0.f);
            pk[4 * p + 0] = f2bf(v.x); pk[4 * p + 1] = f2bf(v.y);
            pk[4 * p + 2] = f2bf(v.z); pk[4 * p + 3] = f2bf(v.w);
        }
        *(uint4*)&lds[m * ST + kq]     = *(uint4*)&pk[0];
        *(uint4*)&lds[m * ST + kq + 8] = *(uint4*)&pk[8];
    }
    // tail features: topic, dde1, 0(dde2), dde3, 0(dde4); pad to KP
    if (t < 32) {
        int gn = nblk + t;
        float vals[10];
#pragma unroll
        for (int i = 0; i < 10; i++) vals[i] = 0.0f;
        if (gn < N) {
            float2 tp = *(const float2*)(topic + 2 * gn);
            float2 d1 = unpack1_mean(acc1_t[gn]);
            float2 d3 = unpack1_mean(acc1_h[gn]);
            vals[0] = tp.x; vals[1] = tp.y;
            vals[2] = d1.x; vals[3] = d1.y;
            // vals[4], vals[5] = dde2 -> deferred to edge_pred
            vals[6] = d3.x; vals[7] = d3.y;
            // vals[8], vals[9] = dde4 -> deferred to edge_pred
        }
#pragma unroll
        for (int i = 0; i < 10; i++) lds[t * ST + EMB + i] = f2bf(vals[i]);
#pragma unroll
        for (int z = 138; z < KP; z++) lds[t * ST + z] = 0;
    }
    __syncthreads();

    f32x4 acc[8];
#pragma unroll
    for (int i = 0; i < 8; i++) acc[i] = (f32x4){0.f, 0.f, 0.f, 0.f};

    const u16* wbbase = WBF + (((size_t)quad * 256 + n0 + ln15) << 3);
#pragma unroll
    for (int ks = 0; ks < 5; ks++) {
        short8 a = *(const short8*)&lds[(m0 + ln15) * ST + ks * 32 + quad * 8];
        const u16* wb = wbbase + ((size_t)ks * 4 * 256 * 8);
#pragma unroll
        for (int nt = 0; nt < 8; nt++) {
            short8 b = *(const short8*)(wb + (nt << 7));
            acc[nt] = __builtin_amdgcn_mfma_f32_16x16x32_bf16(a, b, acc[nt], 0, 0, 0);
        }
    }

    __syncthreads();   // all a-frag reads done before overwrite
#pragma unroll
    for (int nt = 0; nt < 8; nt++) {
        int c = n0 + nt * 16 + ln15;
        float qv = (n0 == 0) ? qWb[c] : 0.0f;
#pragma unroll
        for (int r = 0; r < 4; r++) {
            int row = m0 + quad * 4 + r;
            lds[row * ST + c] = f2bf(acc[nt][r] + qv);
        }
    }
    __syncthreads();
    {
        int m  = t >> 3;
        int c0 = (t & 7) * 32;
        int gn = nblk + m;
        if (gn < N) {
            uint4 v0 = *(uint4*)&lds[m * ST + c0];
            uint4 v1 = *(uint4*)&lds[m * ST + c0 + 8];
            uint4 v2 = *(uint4*)&lds[m * ST + c0 + 16];
            uint4 v3 = *(uint4*)&lds[m * ST + c0 + 24];
            u16* dst = (c0 < 128) ? (A + (size_t)gn * EMB + c0)
                                  : (B + (size_t)gn * EMB + (c0 - 128));
            ((uint4*)dst)[0] = v0;
            ((uint4*)dst)[1] = v1;
            ((uint4*)dst)[2] = v2;
            ((uint4*)dst)[3] = v3;
        }
    }
}

// ---------------------------------------------------------------------------
// T4: per-node deferred tail scalars {dde2.x, dde2.y, dde4.x, dde4.y} (f32)
// ---------------------------------------------------------------------------

__global__ __launch_bounds__(256) void t4_pre(
    const u64* __restrict__ acc1_t, const u64* __restrict__ acc1_h,
    const u64* __restrict__ acc2_t, const u64* __restrict__ acc2_h,
    float4* __restrict__ T4, int N)
{
    int n = blockIdx.x * 256 + threadIdx.x;
    if (n >= N) return;
    const float is20 = 1.0f / 1048576.0f;
    float i1 = is20 / fmaxf((float)(unsigned)(acc1_t[n] >> 42), 1.0f);
    float i2 = is20 / fmaxf((float)(unsigned)(acc1_h[n] >> 42), 1.0f);
    u64 a2 = acc2_t[n], b2v = acc2_h[n];
    T4[n] = make_float4((float)(unsigned)(a2 & 0xFFFFFFFFull) * i1,
                        (float)(unsigned)(a2 >> 32) * i1,
                        (float)(unsigned)(b2v & 0xFFFFFFFFull) * i2,
                        (float)(unsigned)(b2v >> 32) * i2);
}

// ---------------------------------------------------------------------------
// Edge kernel: 16 lanes/edge, grid-stride over edges.
// hidden[j] = A'[h][j] + R[r][j] + B'[t][j]
//           + dde2[h].Wtail + dde4[h].Wtail (A-side rows 132,133,136,137)
//           + dde2[t].Wtail + dde4[t].Wtail (B-side)
// Per-thread 8x8 tail-weight slice lives in VGPRs, loaded once (grid-stride).
// ---------------------------------------------------------------------------

__global__ __launch_bounds__(256) void edge_pred(
    const int* __restrict__ h_id, const int* __restrict__ r_id,
    const int* __restrict__ t_id,
    const u16* __restrict__ A, const u16* __restrict__ B,
    const u16* __restrict__ Rbf, const float4* __restrict__ T4,
    const float* __restrict__ W1,
    const float* __restrict__ W2, const float* __restrict__ b2,
    float* __restrict__ out, int E)
{
    const int tid  = blockIdx.x * 256 + threadIdx.x;
    const int k    = tid & 15;          // j-slice: cols k*8 .. k*8+7
    const int grp  = tid >> 4;          // edge group id
    const int ngrp = (gridDim.x * 256) >> 4;
    const int kj   = k * 8;

    const float4 w0 = *(const float4*)(W2 + kj);
    const float4 w1 = *(const float4*)(W2 + kj + 4);
    const float b2v = b2[0];

    // tail-weight slice: per j, A-side rows {132,133},{136,137}; B-side same
    float2 wA0[8], wA1[8], wB0[8], wB1[8];
#pragma unroll
    for (int j = 0; j < 8; j++) {
        const float* base = W1 + (size_t)(kj + j) * W1LD;
        wA0[j] = *(const float2*)(base + 260);   // Wfull[132..133][j]
        wA1[j] = *(const float2*)(base + 264);   // Wfull[136..137][j]
        wB0[j] = *(const float2*)(base + 526);   // Wfull[132..133][128+j]
        wB1[j] = *(const float2*)(base + 530);   // Wfull[136..137][128+j]
    }

    for (int e = grp; e < E; e += ngrp) {
        const int h = h_id[e], r = r_id[e], tt = t_id[e];
        const uint4 ua = *(const uint4*)(A + (size_t)h * EMB + kj);
        const uint4 ub = *(const uint4*)(B + (size_t)tt * EMB + kj);
        const uint4 ur = *(const uint4*)(Rbf + (size_t)r * EMB + kj);
        const float4 th4 = T4[h];
        const float4 tt4 = T4[tt];

        float av[8], bv[8], rv[8];
        av[0] = bf2f_lo(ua.x); av[1] = bf2f_hi(ua.x);
        av[2] = bf2f_lo(ua.y); av[3] = bf2f_hi(ua.y);
        av[4] = bf2f_lo(ua.z); av[5] = bf2f_hi(ua.z);
        av[6] = bf2f_lo(ua.w); av[7] = bf2f_hi(ua.w);
        bv[0] = bf2f_lo(ub.x); bv[1] = bf2f_hi(ub.x);
        bv[2] = bf2f_lo(ub.y); bv[3] = bf2f_hi(ub.y);
        bv[4] = bf2f_lo(ub.z); bv[5] = bf2f_hi(ub.z);
        bv[6] = bf2f_lo(ub.w); bv[7] = bf2f_hi(ub.w);
        rv[0] = bf2f_lo(ur.x); rv[1] = bf2f_hi(ur.x);
        rv[2] = bf2f_lo(ur.y); rv[3] = bf2f_hi(ur.y);
        rv[4] = bf2f_lo(ur.z); rv[5] = bf2f_hi(ur.z);
        rv[6] = bf2f_lo(ur.w); rv[7] = bf2f_hi(ur.w);
        const float wv[8] = {w0.x, w0.y, w0.z, w0.w, w1.x, w1.y, w1.z, w1.w};

        float s = 0.0f;
#pragma unroll
        for (int j = 0; j < 8; j++) {
            float d = th4.x * wA0[j].x + th4.y * wA0[j].y
                    + th4.z * wA1[j].x + th4.w * wA1[j].y
                    + tt4.x * wB0[j].x + tt4.y * wB0[j].y
                    + tt4.z * wB1[j].x + tt4.w * wB1[j].y;
            s += fmaxf(av[j] + rv[j] + bv[j] + d, 0.0f) * wv[j];
        }
        s += __shfl_xor(s, 1, 64);
        s += __shfl_xor(s, 2, 64);
        s += __shfl_xor(s, 4, 64);
        s += __shfl_xor(s, 8, 64);
        if (k == 0) out[e] = s + b2v;
    }
}

// ---------------------------------------------------------------------------

extern "C" void kernel_launch(void* const* d_in, const int* in_sizes, int n_in,
                              void* d_out, int out_size, void* d_ws, size_t ws_size,
                              hipStream_t stream)
{
    const int*   h_id  = (const int*)d_in[0];
    const int*   r_id  = (const int*)d_in[1];
    const int*   t_id  = (const int*)d_in[2];
    const float* q_emb = (const float*)d_in[3];
    const float* ent   = (const float*)d_in[4];
    const float* rel   = (const float*)d_in[6];
    const float* topic = (const float*)d_in[7];
    const float* nte   = (const float*)d_in[8];
    const float* W1    = (const float*)d_in[9];
    const float* b1    = (const float*)d_in[10];
    const float* W2    = (const float*)d_in[11];
    const float* b2    = (const float*)d_in[12];

    const int E    = in_sizes[0];
    const int NT   = in_sizes[4] / EMB;  // 80000 text entities
    const int N    = in_sizes[7] / 2;    // 100000 total nodes
    const int NREL = in_sizes[6] / EMB;  // 500 relations

    // workspace layout
    u64* acc1_t = (u64*)d_ws;                 // N
    u64* acc1_h = acc1_t + N;                 // N
    u64* acc2_t = acc1_h + N;                 // N
    u64* acc2_h = acc2_t + N;                 // N   (memset region: 4N u64)
    float* qWb  = (float*)(acc2_h + N);       // 128
    u16* Rbf    = (u16*)(qWb + EMB);          // NREL*128 bf16
    u16* WBF    = Rbf + (size_t)NREL * EMB;   // KP*256 bf16
    float4* T4  = (float4*)(WBF + (size_t)KP * 256);  // N float4
    u16* Aw     = (u16*)(T4 + N);             // N*128 bf16
    u16* Bw     = Aw + (size_t)N * EMB;       // N*128 bf16

    hipMemsetAsync(d_ws, 0, sizeof(u64) * (size_t)(4 * N), stream);

    const int ns = (E + 255) / 256;      // scatter blocks
    const int nn = (N + 31) / 32;        // node blocks
    const int nmax = (ns > nn) ? ns : nn;

    k1_scatter1_prep<<<ns + KP + 1 + NREL, 256, 0, stream>>>(
        h_id, t_id, topic, acc1_t, acc1_h,
        W1, q_emb, rel, b1, WBF, qWb, Rbf, E, ns, NREL);

    k2_scatter2_node<<<2 * nmax, 256, 0, stream>>>(
        h_id, t_id, acc1_t, acc1_h, acc2_t, acc2_h,
        ent, nte, topic, WBF, qWb, Aw, Bw, E, ns, NT, N, nn);

    t4_pre<<<(N + 255) / 256, 256, 0, stream>>>(
        acc1_t, acc1_h, acc2_t, acc2_h, T4, N);

    edge_pred<<<2048, 256, 0, stream>>>(h_id, r_id, t_id, Aw, Bw, Rbf, T4,
                                        W1, W2, b2, (float*)d_out, E);
}

// Round 10
// 328.173 us; speedup vs baseline: 1.0665x; 1.0665x over previous
//
#include <hip/hip_runtime.h>

#define EMB 128
#define W1LD 532  // PRED_IN
#define KP 160    // padded K for MFMA (138 -> 160)
#define ST 264    // LDS row stride (u16) in node path

typedef unsigned long long u64;
typedef unsigned short u16;
typedef __attribute__((ext_vector_type(8))) short short8;
typedef __attribute__((ext_vector_type(4))) float f32x4;

__device__ __forceinline__ u16 f2bf(float x) {
    unsigned u = __float_as_uint(x);
    unsigned r = (u + 0x7fffu + ((u >> 16) & 1u)) >> 16;
    return (u16)r;
}
__device__ __forceinline__ float bf2f(u16 u) { return __uint_as_float((unsigned)u << 16); }
__device__ __forceinline__ float bf2f_lo(unsigned u) { return __uint_as_float(u << 16); }
__device__ __forceinline__ float bf2f_hi(unsigned u) { return __uint_as_float(u & 0xffff0000u); }

// round-1 mean, unpacked inline from packed accumulator
__device__ __forceinline__ float2 unpack1_mean(u64 a) {
    float c = (float)(unsigned)(a >> 42);
    float inv = (1.0f / 8192.0f) / fmaxf(c, 1.0f);
    float2 v;
    v.x = (float)(unsigned)(a & 0x1FFFFFull) * inv;
    v.y = (float)(unsigned)((a >> 21) & 0x1FFFFFull) * inv;
    return v;
}

// ---------------------------------------------------------------------------
// K1: scatter1 (blocks 0..ns-1)  ||  prep (blocks ns..)
// scatter pack: [x*2^13:21b][y*2^13:21b][count:22b], 1 u64 atomic/direction
// prep: WBF (bf16 MFMA B-frag order), qWb (f32), Rbf (bf16)
// ---------------------------------------------------------------------------

__global__ __launch_bounds__(256) void k1_scatter1_prep(
    const int* __restrict__ h_id, const int* __restrict__ t_id,
    const float* __restrict__ topic,
    u64* __restrict__ acc_t, u64* __restrict__ acc_h,
    const float* __restrict__ W1, const float* __restrict__ q,
    const float* __restrict__ rel, const float* __restrict__ b1,
    u16* __restrict__ WBF, float* __restrict__ qWb, u16* __restrict__ Rbf,
    int E, int ns, int NREL)
{
    const int bid = blockIdx.x, t = threadIdx.x;
    if (bid < ns) {
        int e = bid * 256 + t;
        if (e >= E) return;
        int h = h_id[e], tt = t_id[e];
        float2 th = *(const float2*)(topic + 2 * h);
        float2 tv = *(const float2*)(topic + 2 * tt);
        u64 p1 = (u64)__float2uint_rn(th.x * 8192.0f)
               | ((u64)__float2uint_rn(th.y * 8192.0f) << 21)
               | (1ull << 42);
        u64 p3 = (u64)__float2uint_rn(tv.x * 8192.0f)
               | ((u64)__float2uint_rn(tv.y * 8192.0f) << 21)
               | (1ull << 42);
        atomicAdd(&acc_t[tt], p1);
        atomicAdd(&acc_h[h], p3);
        return;
    }
    const int pb = bid - ns;
    if (pb < KP) {
        int k = pb, n = t;
        float v = 0.0f;
        if (k < 138) {
            v = (n < 128) ? W1[(size_t)n * W1LD + 128 + k]
                          : W1[(size_t)(n - 128) * W1LD + 394 + k];
        }
        int kstep = k >> 5, quad = (k >> 3) & 3, j = k & 7;
        WBF[(((size_t)(kstep * 4 + quad) * 256 + n) << 3) + j] = f2bf(v);
        return;
    }
    int b = pb - KP;   // 0 -> qWb ; 1..NREL -> relation b-1
    __shared__ float v[EMB];
    if (t < EMB) v[t] = (b == 0) ? q[t] : rel[(size_t)(b - 1) * EMB + t];
    __syncthreads();
    if (t < EMB) {
        const float* w = W1 + (size_t)t * W1LD + (b == 0 ? 0 : 266);
        float s = 0.0f;
#pragma unroll
        for (int k = 0; k < EMB; k += 4) {
            float4 wv = *(const float4*)(w + k);
            s += wv.x * v[k] + wv.y * v[k + 1] + wv.z * v[k + 2] + wv.w * v[k + 3];
        }
        if (b == 0) qWb[t] = s + b1[t];
        else        Rbf[(size_t)(b - 1) * EMB + t] = f2bf(s);
    }
}

// ---------------------------------------------------------------------------
// K2: interleaved  odd blocks -> scatter2 ; even blocks -> node MFMA GEMM.
// node computes A/B with ALL 8 dde tail dims zeroed (deferred to K3 fixup);
// it reads NO accumulators -> race-free vs concurrent scatter2.
// Round 2 pack: [x*2^20 : 32b][y*2^20 : 32b]
// ---------------------------------------------------------------------------

__global__ __launch_bounds__(256) void k2_scatter2_node(
    const int* __restrict__ h_id, const int* __restrict__ t_id,
    const u64* __restrict__ acc1_t, const u64* __restrict__ acc1_h,
    u64* __restrict__ acc2_t, u64* __restrict__ acc2_h,
    const float* __restrict__ ent, const float* __restrict__ nte,
    const float* __restrict__ topic,
    const u16* __restrict__ WBF, const float* __restrict__ qWb,
    u16* __restrict__ A, u16* __restrict__ B,
    int E, int ns, int NT, int N, int nn)
{
    __shared__ __align__(16) u16 lds[32 * ST];
    const int bid = blockIdx.x, t = threadIdx.x;
    const int half = bid >> 1;

    if (bid & 1) {
        // ---------------- scatter2 ----------------
        if (half >= ns) return;
        int e = half * 256 + t;
        if (e >= E) return;
        int h = h_id[e], tt = t_id[e];
        float2 v1 = unpack1_mean(acc1_t[h]);   // dde1[h]
        float2 v3 = unpack1_mean(acc1_h[tt]);  // dde3[t]
        const float sc = 1048576.0f;  // 2^20
        u64 p2 = (u64)__float2uint_rn(v1.x * sc)
               | ((u64)__float2uint_rn(v1.y * sc) << 32);
        u64 p4 = (u64)__float2uint_rn(v3.x * sc)
               | ((u64)__float2uint_rn(v3.y * sc) << 32);
        atomicAdd(&acc2_t[tt], p2);
        atomicAdd(&acc2_h[h], p4);
        return;
    }

    // ---------------- node GEMM (partial: no dde dims) ----------------
    if (half >= nn) return;
    const int lane = t & 63;
    const int w    = t >> 6;
    const int ln15 = lane & 15;
    const int quad = lane >> 4;
    const int m0   = (w & 1) * 16;
    const int n0   = (w >> 1) * 128;
    const int nblk = half * 32;

    {   // stage dense features as bf16: thread -> node m=t>>3, 16 k-elems
        int m  = t >> 3;
        int kq = (t & 7) << 4;
        int gn = nblk + m;
        const float* src = (gn < N) ? ((gn < NT) ? ent + (size_t)gn * EMB + kq
                                                 : nte + kq)
                                    : nte;
        u16 pk[16];
#pragma unroll
        for (int p = 0; p < 4; p++) {
            float4 v = (gn < N) ? *(const float4*)(src + 4 * p)
                                : make_float4(0.f, 0.f, 0.f, 0.f);
            pk[4 * p + 0] = f2bf(v.x); pk[4 * p + 1] = f2bf(v.y);
            pk[4 * p + 2] = f2bf(v.z); pk[4 * p + 3] = f2bf(v.w);
        }
        *(uint4*)&lds[m * ST + kq]     = *(uint4*)&pk[0];
        *(uint4*)&lds[m * ST + kq + 8] = *(uint4*)&pk[8];
    }
    // tail: topic only (k=128,129); k=130..159 zero (dde deferred to fixup)
    if (t < 32) {
        int gn = nblk + t;
        float2 tp = (gn < N) ? *(const float2*)(topic + 2 * gn)
                             : make_float2(0.f, 0.f);
        lds[t * ST + 128] = f2bf(tp.x);
        lds[t * ST + 129] = f2bf(tp.y);
#pragma unroll
        for (int z = 130; z < KP; z++) lds[t * ST + z] = 0;
    }
    __syncthreads();

    f32x4 acc[8];
#pragma unroll
    for (int i = 0; i < 8; i++) acc[i] = (f32x4){0.f, 0.f, 0.f, 0.f};

    const u16* wbbase = WBF + (((size_t)quad * 256 + n0 + ln15) << 3);
#pragma unroll
    for (int ks = 0; ks < 5; ks++) {
        short8 a = *(const short8*)&lds[(m0 + ln15) * ST + ks * 32 + quad * 8];
        const u16* wb = wbbase + ((size_t)ks * 4 * 256 * 8);
#pragma unroll
        for (int nt = 0; nt < 8; nt++) {
            short8 b = *(const short8*)(wb + (nt << 7));
            acc[nt] = __builtin_amdgcn_mfma_f32_16x16x32_bf16(a, b, acc[nt], 0, 0, 0);
        }
    }

    __syncthreads();   // all a-frag reads done before overwrite
#pragma unroll
    for (int nt = 0; nt < 8; nt++) {
        int c = n0 + nt * 16 + ln15;
        float qv = (n0 == 0) ? qWb[c] : 0.0f;
#pragma unroll
        for (int r = 0; r < 4; r++) {
            int row = m0 + quad * 4 + r;
            lds[row * ST + c] = f2bf(acc[nt][r] + qv);
        }
    }
    __syncthreads();
    {
        int m  = t >> 3;
        int c0 = (t & 7) * 32;
        int gn = nblk + m;
        if (gn < N) {
            uint4 v0 = *(uint4*)&lds[m * ST + c0];
            uint4 v1 = *(uint4*)&lds[m * ST + c0 + 8];
            uint4 v2 = *(uint4*)&lds[m * ST + c0 + 16];
            uint4 v3 = *(uint4*)&lds[m * ST + c0 + 24];
            u16* dst = (c0 < 128) ? (A + (size_t)gn * EMB + c0)
                                  : (B + (size_t)gn * EMB + (c0 - 128));
            ((uint4*)dst)[0] = v0;
            ((uint4*)dst)[1] = v1;
            ((uint4*)dst)[2] = v2;
            ((uint4*)dst)[3] = v3;
        }
    }
}

// ---------------------------------------------------------------------------
// K3 fixup: per-node rank-8 tail correction, A/B updated in place.
// tail vals tv[8] = {dde1.x,dde1.y,dde2.x,dde2.y,dde3.x,dde3.y,dde4.x,dde4.y}
// A[n][j] += sum_m tv[m] * W1[j][258+m]   (Wfull[130+m][j])
// B[n][j] += sum_m tv[m] * W1[j][524+m]   (Wfull[130+m][128+j])
// Block: 32 nodes x 256 threads (thread = column; <128 -> A, else B).
// ---------------------------------------------------------------------------

__global__ __launch_bounds__(256) void k3_fixup(
    const u64* __restrict__ acc1_t, const u64* __restrict__ acc1_h,
    const u64* __restrict__ acc2_t, const u64* __restrict__ acc2_h,
    const float* __restrict__ W1,
    u16* __restrict__ A, u16* __restrict__ B, int N)
{
    __shared__ float tvs[32][8];
    const int t = threadIdx.x;
    const int nblk = blockIdx.x * 32;

    if (t < 32) {
        int gn = nblk + t;
        float tv[8];
#pragma unroll
        for (int i = 0; i < 8; i++) tv[i] = 0.0f;
        if (gn < N) {
            u64 a1 = acc1_t[gn], b1v = acc1_h[gn];
            float2 d1 = unpack1_mean(a1);
            float2 d3 = unpack1_mean(b1v);
            const float is20 = 1.0f / 1048576.0f;
            float i1 = is20 / fmaxf((float)(unsigned)(a1 >> 42), 1.0f);
            float i2 = is20 / fmaxf((float)(unsigned)(b1v >> 42), 1.0f);
            u64 a2 = acc2_t[gn], b2v = acc2_h[gn];
            tv[0] = d1.x; tv[1] = d1.y;
            tv[2] = (float)(unsigned)(a2 & 0xFFFFFFFFull) * i1;   // dde2
            tv[3] = (float)(unsigned)(a2 >> 32) * i1;
            tv[4] = d3.x; tv[5] = d3.y;
            tv[6] = (float)(unsigned)(b2v & 0xFFFFFFFFull) * i2;  // dde4
            tv[7] = (float)(unsigned)(b2v >> 32) * i2;
        }
#pragma unroll
        for (int i = 0; i < 8; i++) tvs[t][i] = tv[i];
    }

    // per-thread tail weights: contiguous 8 floats
    const int c = t & 127;
    const float* wp = W1 + (size_t)c * W1LD + ((t < 128) ? 258 : 524);
    float4 wv0 = *(const float4*)(wp);
    float4 wv1 = *(const float4*)(wp + 4);
    u16* dst = (t < 128) ? (A + c) : (B + c);
    __syncthreads();

#pragma unroll 4
    for (int m = 0; m < 32; m++) {
        int gn = nblk + m;
        if (gn >= N) break;
        const float* tv = tvs[m];
        float d = tv[0] * wv0.x + tv[1] * wv0.y + tv[2] * wv0.z + tv[3] * wv0.w
                + tv[4] * wv1.x + tv[5] * wv1.y + tv[6] * wv1.z + tv[7] * wv1.w;
        u16* p = dst + (size_t)gn * EMB;
        *p = f2bf(bf2f(*p) + d);
    }
}

// ---------------------------------------------------------------------------
// K4 edge kernel: 16 lanes/edge, 8 elems/lane, 4 edges/wave; uint4 gathers.
// pred[e] = W2 . relu(A[h] + R[r] + B[t]) + b2
// ---------------------------------------------------------------------------

__global__ __launch_bounds__(256) void edge_pred(
    const int* __restrict__ h_id, const int* __restrict__ r_id,
    const int* __restrict__ t_id,
    const u16* __restrict__ A, const u16* __restrict__ B,
    const u16* __restrict__ Rbf,
    const float* __restrict__ W2, const float* __restrict__ b2,
    float* __restrict__ out, int E)
{
    const int t    = threadIdx.x;
    const int lane = t & 63;
    const int g    = lane >> 4;
    const int k    = lane & 15;
    const int wv   = t >> 6;
    const int e    = blockIdx.x * 16 + wv * 4 + g;

    const float4 w0 = *(const float4*)(W2 + k * 8);
    const float4 w1 = *(const float4*)(W2 + k * 8 + 4);

    float s = 0.0f;
    if (e < E) {
        const int h = h_id[e], r = r_id[e], tt = t_id[e];
        const uint4 ua = *(const uint4*)(A + (size_t)h * EMB + k * 8);
        const uint4 ub = *(const uint4*)(B + (size_t)tt * EMB + k * 8);
        const uint4 ur = *(const uint4*)(Rbf + (size_t)r * EMB + k * 8);

        s  = fmaxf(bf2f_lo(ua.x) + bf2f_lo(ur.x) + bf2f_lo(ub.x), 0.0f) * w0.x;
        s += fmaxf(bf2f_hi(ua.x) + bf2f_hi(ur.x) + bf2f_hi(ub.x), 0.0f) * w0.y;
        s += fmaxf(bf2f_lo(ua.y) + bf2f_lo(ur.y) + bf2f_lo(ub.y), 0.0f) * w0.z;
        s += fmaxf(bf2f_hi(ua.y) + bf2f_hi(ur.y) + bf2f_hi(ub.y), 0.0f) * w0.w;
        s += fmaxf(bf2f_lo(ua.z) + bf2f_lo(ur.z) + bf2f_lo(ub.z), 0.0f) * w1.x;
        s += fmaxf(bf2f_hi(ua.z) + bf2f_hi(ur.z) + bf2f_hi(ub.z), 0.0f) * w1.y;
        s += fmaxf(bf2f_lo(ua.w) + bf2f_lo(ur.w) + bf2f_lo(ub.w), 0.0f) * w1.z;
        s += fmaxf(bf2f_hi(ua.w) + bf2f_hi(ur.w) + bf2f_hi(ub.w), 0.0f) * w1.w;
    }
    s += __shfl_xor(s, 1, 64);
    s += __shfl_xor(s, 2, 64);
    s += __shfl_xor(s, 4, 64);
    s += __shfl_xor(s, 8, 64);
    if (k == 0 && e < E) out[e] = s + b2[0];
}

// ---------------------------------------------------------------------------

extern "C" void kernel_launch(void* const* d_in, const int* in_sizes, int n_in,
                              void* d_out, int out_size, void* d_ws, size_t ws_size,
                              hipStream_t stream)
{
    const int*   h_id  = (const int*)d_in[0];
    const int*   r_id  = (const int*)d_in[1];
    const int*   t_id  = (const int*)d_in[2];
    const float* q_emb = (const float*)d_in[3];
    const float* ent   = (const float*)d_in[4];
    const float* rel   = (const float*)d_in[6];
    const float* topic = (const float*)d_in[7];
    const float* nte   = (const float*)d_in[8];
    const float* W1    = (const float*)d_in[9];
    const float* b1    = (const float*)d_in[10];
    const float* W2    = (const float*)d_in[11];
    const float* b2    = (const float*)d_in[12];

    const int E    = in_sizes[0];
    const int NT   = in_sizes[4] / EMB;  // 80000 text entities
    const int N    = in_sizes[7] / 2;    // 100000 total nodes
    const int NREL = in_sizes[6] / EMB;  // 500 relations

    // workspace layout
    u64* acc1_t = (u64*)d_ws;                 // N
    u64* acc1_h = acc1_t + N;                 // N
    u64* acc2_t = acc1_h + N;                 // N
    u64* acc2_h = acc2_t + N;                 // N   (memset region: 4N u64)
    float* qWb  = (float*)(acc2_h + N);       // 128
    u16* Rbf    = (u16*)(qWb + EMB);          // NREL*128 bf16
    u16* WBF    = Rbf + (size_t)NREL * EMB;   // KP*256 bf16
    u16* Aw     = WBF + (size_t)KP * 256;     // N*128 bf16
    u16* Bw     = Aw + (size_t)N * EMB;       // N*128 bf16

    hipMemsetAsync(d_ws, 0, sizeof(u64) * (size_t)(4 * N), stream);

    const int ns = (E + 255) / 256;      // scatter blocks
    const int nn = (N + 31) / 32;        // node blocks
    const int nmax = (ns > nn) ? ns : nn;

    k1_scatter1_prep<<<ns + KP + 1 + NREL, 256, 0, stream>>>(
        h_id, t_id, topic, acc1_t, acc1_h,
        W1, q_emb, rel, b1, WBF, qWb, Rbf, E, ns, NREL);

    k2_scatter2_node<<<2 * nmax, 256, 0, stream>>>(
        h_id, t_id, acc1_t, acc1_h, acc2_t, acc2_h,
        ent, nte, topic, WBF, qWb, Aw, Bw, E, ns, NT, N, nn);

    k3_fixup<<<(N + 31) / 32, 256, 0, stream>>>(
        acc1_t, acc1_h, acc2_t, acc2_h, W1, Aw, Bw, N);

    edge_pred<<<(E + 15) / 16, 256, 0, stream>>>(
        h_id, r_id, t_id, Aw, Bw, Rbf, W2, b2, (float*)d_out, E);
}